// Round 1
// baseline (111.216 us; speedup 1.0000x reference)
//
#include <hip/hip_runtime.h>
#include <math.h>

#define BATCH 32
#define SEQ   4096
#define HD    1024

// ---------------------------------------------------------------------------
// Pass 1: fused score + online-softmax + weighted-accumulate over a chunk of
// source positions. One read of `values` from HBM total.
// Grid: BATCH * CPB blocks, 256 threads (4 waves). Each wave processes
// SEQ/CPB/4 consecutive rows; a row (1024 f32) lives entirely in the wave's
// registers (16 f32/lane) between the dot product and the accumulation.
// ---------------------------------------------------------------------------
template <int CPB>
__global__ __launch_bounds__(256)
void luong_pass1(const float* __restrict__ q,
                 const float* __restrict__ v,
                 const float* __restrict__ scale,
                 float* __restrict__ ws_acc,   // [BATCH*CPB][HD]
                 float* __restrict__ ws_m,     // [BATCH*CPB]
                 float* __restrict__ ws_l)     // [BATCH*CPB]
{
    constexpr int ROWS = SEQ / CPB;   // rows per block
    constexpr int RPW  = ROWS / 4;    // rows per wave
    const int blk  = blockIdx.x;
    const int b    = blk / CPB;
    const int ch   = blk % CPB;
    const int tid  = threadIdx.x;
    const int wid  = tid >> 6;
    const int lane = tid & 63;

    // Query fragment: lane holds h = k*256 + lane*4 + {0..3}, k = 0..3.
    const float4* q4 = (const float4*)(q + (size_t)b * HD);
    float4 qf[4];
#pragma unroll
    for (int k = 0; k < 4; ++k) qf[k] = q4[k * 64 + lane];

    float  m = -INFINITY, l = 0.f;
    float4 acc[4];
#pragma unroll
    for (int k = 0; k < 4; ++k) acc[k] = make_float4(0.f, 0.f, 0.f, 0.f);

    const int s0 = ch * ROWS + wid * RPW;
    for (int r = 0; r < RPW; ++r) {
        const int s = s0 + r;
        const float4* v4 = (const float4*)(v + ((size_t)b * SEQ + s) * HD);
        float4 vf[4];
#pragma unroll
        for (int k = 0; k < 4; ++k) vf[k] = v4[k * 64 + lane];  // coalesced 1KB/wave

        // dot(values[b,s,:], query[b,:])
        float d = 0.f;
#pragma unroll
        for (int k = 0; k < 4; ++k)
            d += vf[k].x * qf[k].x + vf[k].y * qf[k].y
               + vf[k].z * qf[k].z + vf[k].w * qf[k].w;
#pragma unroll
        for (int off = 32; off >= 1; off >>= 1)
            d += __shfl_xor(d, off, 64);

        const float sc = d * scale[s];
        // sc and m are wave-uniform -> no divergence on this branch.
        if (sc <= m) {
            const float p = __expf(sc - m);
            l += p;
#pragma unroll
            for (int k = 0; k < 4; ++k) {
                acc[k].x += p * vf[k].x;  acc[k].y += p * vf[k].y;
                acc[k].z += p * vf[k].z;  acc[k].w += p * vf[k].w;
            }
        } else {
            const float f = __expf(m - sc);  // first row: exp(-inf)=0 zeroes acc
            l = l * f + 1.f;                 // p = exp(sc - sc) = 1
#pragma unroll
            for (int k = 0; k < 4; ++k) {
                acc[k].x = acc[k].x * f + vf[k].x;
                acc[k].y = acc[k].y * f + vf[k].y;
                acc[k].z = acc[k].z * f + vf[k].z;
                acc[k].w = acc[k].w * f + vf[k].w;
            }
            m = sc;
        }
    }

    // ---- combine the 4 waves of this block through LDS ----
    __shared__ float lds_m[4], lds_l[4];
    __shared__ float lds_acc[4][HD];
    if (lane == 0) { lds_m[wid] = m; lds_l[wid] = l; }
    __syncthreads();
    const float M  = fmaxf(fmaxf(lds_m[0], lds_m[1]), fmaxf(lds_m[2], lds_m[3]));
    const float fw = __expf(m - M);
    float4* la = (float4*)lds_acc[wid];
#pragma unroll
    for (int k = 0; k < 4; ++k) {
        float4 t;
        t.x = acc[k].x * fw; t.y = acc[k].y * fw;
        t.z = acc[k].z * fw; t.w = acc[k].w * fw;
        la[k * 64 + lane] = t;   // linear h layout: float4 index k*64+lane
    }
    __syncthreads();

    float lblk = 0.f;
#pragma unroll
    for (int w = 0; w < 4; ++w) lblk += lds_l[w] * __expf(lds_m[w] - M);

    // thread tid sums h = 4*tid .. 4*tid+3 across the 4 waves
    const float4 a0 = ((const float4*)lds_acc[0])[tid];
    const float4 a1 = ((const float4*)lds_acc[1])[tid];
    const float4 a2 = ((const float4*)lds_acc[2])[tid];
    const float4 a3 = ((const float4*)lds_acc[3])[tid];
    float4 sum;
    sum.x = a0.x + a1.x + a2.x + a3.x;
    sum.y = a0.y + a1.y + a2.y + a3.y;
    sum.z = a0.z + a1.z + a2.z + a3.z;
    sum.w = a0.w + a1.w + a2.w + a3.w;
    ((float4*)(ws_acc + (size_t)blk * HD))[tid] = sum;
    if (tid == 0) { ws_m[blk] = M; ws_l[blk] = lblk; }
}

// ---------------------------------------------------------------------------
// Pass 2: combine the CPB partials of each batch and normalize.
// Grid: BATCH blocks, 256 threads. Tiny (~4 MB read).
// ---------------------------------------------------------------------------
template <int CPB>
__global__ __launch_bounds__(256)
void luong_pass2(const float* __restrict__ ws_acc,
                 const float* __restrict__ ws_m,
                 const float* __restrict__ ws_l,
                 float* __restrict__ out)
{
    const int b   = blockIdx.x;
    const int tid = threadIdx.x;

    float M = -INFINITY;
#pragma unroll
    for (int i = 0; i < CPB; ++i) M = fmaxf(M, ws_m[b * CPB + i]);
    float T = 0.f;
#pragma unroll
    for (int i = 0; i < CPB; ++i) T += ws_l[b * CPB + i] * __expf(ws_m[b * CPB + i] - M);
    const float invT = 1.f / T;

    float4 sum = make_float4(0.f, 0.f, 0.f, 0.f);
#pragma unroll
    for (int i = 0; i < CPB; ++i) {
        const float wi = __expf(ws_m[b * CPB + i] - M) * invT;
        const float4 a = ((const float4*)(ws_acc + (size_t)(b * CPB + i) * HD))[tid];
        sum.x += wi * a.x; sum.y += wi * a.y;
        sum.z += wi * a.z; sum.w += wi * a.w;
    }
    ((float4*)(out + (size_t)b * HD))[tid] = sum;
}

// ---------------------------------------------------------------------------
template <int CPB>
static void launch_impl(const float* q, const float* v, const float* scale,
                        float* out, float* ws, hipStream_t stream)
{
    const int NB = BATCH * CPB;
    float* ws_acc = ws;
    float* ws_m   = ws + (size_t)NB * HD;
    float* ws_l   = ws_m + NB;
    luong_pass1<CPB><<<NB, 256, 0, stream>>>(q, v, scale, ws_acc, ws_m, ws_l);
    luong_pass2<CPB><<<BATCH, 256, 0, stream>>>(ws_acc, ws_m, ws_l, out);
}

extern "C" void kernel_launch(void* const* d_in, const int* in_sizes, int n_in,
                              void* d_out, int out_size, void* d_ws, size_t ws_size,
                              hipStream_t stream)
{
    const float* q     = (const float*)d_in[0];   // [B, H]
    const float* v     = (const float*)d_in[1];   // [B, S, H]
    const float* scale = (const float*)d_in[2];   // [S, 1]
    float* out = (float*)d_out;                   // [B, H]
    float* ws  = (float*)d_ws;

    // pick the largest CPB whose partials fit in the workspace
    int cpb = 32;
    while (cpb > 1 &&
           (size_t)BATCH * cpb * (HD + 2) * sizeof(float) > ws_size)
        cpb >>= 1;

    switch (cpb) {
        case 32: launch_impl<32>(q, v, scale, out, ws, stream); break;
        case 16: launch_impl<16>(q, v, scale, out, ws, stream); break;
        case 8:  launch_impl<8>(q, v, scale, out, ws, stream); break;
        case 4:  launch_impl<4>(q, v, scale, out, ws, stream); break;
        case 2:  launch_impl<2>(q, v, scale, out, ws, stream); break;
        default: launch_impl<1>(q, v, scale, out, ws, stream); break;
    }
}